// Round 20
// baseline (114.156 us; speedup 1.0000x reference)
//
#include <hip/hip_runtime.h>
#include <hip/hip_bf16.h>
#include <stdint.h>

typedef __bf16 bf16;
typedef __bf16 bf16x8 __attribute__((ext_vector_type(8)));
typedef __bf16 bf16x4 __attribute__((ext_vector_type(4)));
typedef float f32x4 __attribute__((ext_vector_type(4)));
typedef float f32x16 __attribute__((ext_vector_type(16)));
typedef unsigned int u32;

#define B_  2
#define S_  2048
#define D_  1024
#define H_  16
#define HD_ 64

typedef __attribute__((address_space(1))) uint32_t gu32;
typedef __attribute__((address_space(3))) uint32_t lu32;

__device__ __forceinline__ void gload16(void* lds, const void* g) {
  __builtin_amdgcn_global_load_lds((const gu32*)(uintptr_t)g,
                                   (lu32*)(uint32_t)(uintptr_t)lds,
                                   16, 0, 0);
}

// ---------------------------------------- prep: wtrans (ids 0..1023) + cast x
__global__ __launch_bounds__(256) void prep(
    const float* __restrict__ x,
    const float* __restrict__ w0, const float* __restrict__ w1,
    const float* __restrict__ w2, const float* __restrict__ w3,
    bf16* __restrict__ xb, bf16* __restrict__ wt) {
  __shared__ float tile[64][65];
  int id = blockIdx.x;
  if (id < 1024) {
    int z = id >> 8, rem = id & 255;
    const float* src = (z == 0) ? w0 : (z == 1) ? w1 : (z == 2) ? w2 : w3;
    bf16* dst = wt + ((size_t)z << 20);
    int x0 = (rem & 15) * 64, y0 = (rem >> 4) * 64;
    int tx = threadIdx.x & 63, ty = threadIdx.x >> 6;  // 64 x 4
#pragma unroll
    for (int r = 0; r < 16; ++r)
      tile[ty + r * 4][tx] = src[(size_t)(y0 + ty + r * 4) * D_ + x0 + tx];
    __syncthreads();
#pragma unroll
    for (int r = 0; r < 16; ++r)
      dst[(size_t)(x0 + ty + r * 4) * D_ + y0 + tx] = (bf16)tile[tx][ty + r * 4];
  } else {
    int cid = id - 1024;  // 1024 blocks x 256 threads x 4 float4 = 4M floats
    int base = cid * 1024 + threadIdx.x;
#pragma unroll
    for (int r = 0; r < 4; ++r) {
      int i = base + r * 256;
      float4 v = ((const float4*)x)[i];
      bf16x4 o = {(bf16)v.x, (bf16)v.y, (bf16)v.z, (bf16)v.w};
      ((bf16x4*)xb)[i] = o;
    }
  }
}

// ------------------------------------------------- fused QKV projection
// Pipelined K-loop (counted vmcnt(8)) + persistent grid-stride + XOR-swizzle.
__global__ __launch_bounds__(256) void gemm_qkv(
    const bf16* __restrict__ A, const bf16* __restrict__ Bt,
    const float* __restrict__ bq, const float* __restrict__ bk,
    const float* __restrict__ bv,
    bf16* __restrict__ qb, bf16* __restrict__ kb, bf16* __restrict__ vtb) {
  __shared__ __align__(16) bf16 smem[4 * 128 * 64];  // As[2] | Bs[2] = 64 KB
  const int K = D_;
  int tid = threadIdx.x;
  int lane = tid & 63, wid = tid >> 6;
  int ln15 = lane & 15, lg = lane >> 4;
  int wr = wid >> 1, wc = wid & 1;
  int rl = lane >> 3;
  int sch = (lane & 7) ^ rl;  // inverse-swizzled source chunk
  int r7 = ln15 & 7;          // row&7 of every fragment row this lane reads

  for (int tile = blockIdx.x; tile < 768; tile += 512) {
    int m0 = (tile / 24) * 128, n0g = (tile % 24) * 128;

    f32x4 acc[4][4] = {};

    auto stage = [&](int cc, int t) {
      int k0 = t * 64;
#pragma unroll
      for (int i = 0; i < 4; ++i) {
        int rr = i * 32 + wid * 8;  // 8-row group base (linear LDS dest)
        gload16(&smem[cc * 8192 + rr * 64],
                A + (size_t)(m0 + rr + rl) * K + k0 + sch * 8);
        gload16(&smem[16384 + cc * 8192 + rr * 64],
                Bt + (size_t)(n0g + rr + rl) * K + k0 + sch * 8);
      }
    };

    const int nt = K / 64;  // 16
    stage(0, 0);
    stage(1, 1);

    for (int t = 0; t < nt; ++t) {
      int cur = t & 1;
      if (t + 1 < nt) { asm volatile("s_waitcnt vmcnt(8)" ::: "memory"); }
      else            { asm volatile("s_waitcnt vmcnt(0)" ::: "memory"); }
      __builtin_amdgcn_sched_barrier(0);
      __builtin_amdgcn_s_barrier();
      __builtin_amdgcn_sched_barrier(0);

      const bf16* Asb = &smem[cur * 8192];
      const bf16* Bsb = &smem[16384 + cur * 8192];
#pragma unroll
      for (int kk = 0; kk < 64; kk += 32) {
        int chb = kk >> 3;  // chunk base (0 or 4)
        bf16x8 af[4], bfr[4];
#pragma unroll
        for (int tt = 0; tt < 4; ++tt)
          af[tt] = *(const bf16x8*)&Asb[(wr * 64 + tt * 16 + ln15) * 64 +
                                        (((chb + lg) ^ r7) * 8)];
#pragma unroll
        for (int tt = 0; tt < 4; ++tt)
          bfr[tt] = *(const bf16x8*)&Bsb[(wc * 64 + tt * 16 + ln15) * 64 +
                                         (((chb + lg) ^ r7) * 8)];
#pragma unroll
        for (int mi = 0; mi < 4; ++mi)
#pragma unroll
          for (int ni = 0; ni < 4; ++ni)
            acc[mi][ni] = __builtin_amdgcn_mfma_f32_16x16x32_bf16(
                af[mi], bfr[ni], acc[mi][ni], 0, 0, 0);
      }

      __builtin_amdgcn_s_barrier();  // reads of buf[cur] complete (reg deps)
      if (t + 2 < nt) stage(cur, t + 2);
    }

    int seg = n0g >> 10;  // block-uniform (128 | 1024)
    int n0 = n0g & 1023;

    if (seg == 2) {
      bf16 (*tr)[136] = (bf16(*)[136])smem;
#pragma unroll
      for (int ni = 0; ni < 4; ++ni) {
        int nl = wc * 64 + ni * 16 + ln15;
        float bvl = bv[n0 + nl];
#pragma unroll
        for (int mi = 0; mi < 4; ++mi) {
          int ml = wr * 64 + mi * 16 + lg * 4;
          bf16x4 pk = {(bf16)(acc[mi][ni][0] + bvl), (bf16)(acc[mi][ni][1] + bvl),
                       (bf16)(acc[mi][ni][2] + bvl), (bf16)(acc[mi][ni][3] + bvl)};
          *(bf16x4*)&tr[nl][ml] = pk;
        }
      }
      __syncthreads();
      int r = tid >> 1, hf = tid & 1;
      int n = n0 + r;
      int hh = n >> 6, dd = n & 63;
      int bb = m0 >> 11, s0c = (m0 & 2047) + hf * 64;
      bf16* dst = vtb + (((size_t)bb * H_ + hh) * HD_ + dd) * S_ + s0c;
      const bf16* srcr = &tr[r][hf * 64];
#pragma unroll
      for (int k = 0; k < 8; ++k)
        *(bf16x8*)&dst[k * 8] = *(const bf16x8*)&srcr[k * 8];
    } else {
      const float* bias = (seg == 0) ? bq : bk;
      bf16* outp = (seg == 0) ? qb : kb;
#pragma unroll
      for (int ni = 0; ni < 4; ++ni) {
        int n = n0 + wc * 64 + ni * 16 + ln15;
        float bvl = bias[n];
#pragma unroll
        for (int mi = 0; mi < 4; ++mi) {
          int mb = m0 + wr * 64 + mi * 16 + lg * 4;
#pragma unroll
          for (int j = 0; j < 4; ++j)
            outp[(size_t)(mb + j) * D_ + n] = (bf16)(acc[mi][ni][j] + bvl);
        }
      }
    }
    __syncthreads();  // protect smem before next tile's staging
  }
}

// ------------------------------------------- GEMM (O-proj), same pipeline
__global__ __launch_bounds__(256) void gemm128(
    const bf16* __restrict__ A, const bf16* __restrict__ Bt,
    const float* __restrict__ bias, float* __restrict__ outf,
    int M, int N, int K) {
  __shared__ __align__(16) bf16 smem[4 * 128 * 64];  // As[2] | Bs[2]
  int tid = threadIdx.x;
  int lane = tid & 63, wid = tid >> 6;
  int ln15 = lane & 15, lg = lane >> 4;
  int wr = wid >> 1, wc = wid & 1;
  int m0 = blockIdx.y * 128, n0 = blockIdx.x * 128;
  int rl = lane >> 3;
  int sch = (lane & 7) ^ rl;
  int r7 = ln15 & 7;

  f32x4 acc[4][4] = {};

  auto stage = [&](int cc, int t) {
    int k0 = t * 64;
#pragma unroll
    for (int i = 0; i < 4; ++i) {
      int rr = i * 32 + wid * 8;
      gload16(&smem[cc * 8192 + rr * 64],
              A + (size_t)(m0 + rr + rl) * K + k0 + sch * 8);
      gload16(&smem[16384 + cc * 8192 + rr * 64],
              Bt + (size_t)(n0 + rr + rl) * K + k0 + sch * 8);
    }
  };

  const int nt = K / 64;
  stage(0, 0);
  stage(1, 1);

  for (int t = 0; t < nt; ++t) {
    int cur = t & 1;
    if (t + 1 < nt) { asm volatile("s_waitcnt vmcnt(8)" ::: "memory"); }
    else            { asm volatile("s_waitcnt vmcnt(0)" ::: "memory"); }
    __builtin_amdgcn_sched_barrier(0);
    __builtin_amdgcn_s_barrier();
    __builtin_amdgcn_sched_barrier(0);

    const bf16* Asb = &smem[cur * 8192];
    const bf16* Bsb = &smem[16384 + cur * 8192];
#pragma unroll
    for (int kk = 0; kk < 64; kk += 32) {
      int chb = kk >> 3;
      bf16x8 af[4], bfr[4];
#pragma unroll
      for (int tt = 0; tt < 4; ++tt)
        af[tt] = *(const bf16x8*)&Asb[(wr * 64 + tt * 16 + ln15) * 64 +
                                      (((chb + lg) ^ r7) * 8)];
#pragma unroll
      for (int tt = 0; tt < 4; ++tt)
        bfr[tt] = *(const bf16x8*)&Bsb[(wc * 64 + tt * 16 + ln15) * 64 +
                                       (((chb + lg) ^ r7) * 8)];
#pragma unroll
      for (int mi = 0; mi < 4; ++mi)
#pragma unroll
        for (int ni = 0; ni < 4; ++ni)
          acc[mi][ni] = __builtin_amdgcn_mfma_f32_16x16x32_bf16(
              af[mi], bfr[ni], acc[mi][ni], 0, 0, 0);
    }

    __builtin_amdgcn_s_barrier();
    if (t + 2 < nt) stage(cur, t + 2);
  }

#pragma unroll
  for (int ni = 0; ni < 4; ++ni) {
    int n = n0 + wc * 64 + ni * 16 + ln15;
    float bvl = bias[n];
#pragma unroll
    for (int mi = 0; mi < 4; ++mi) {
      int mb = m0 + wr * 64 + mi * 16 + lg * 4;
#pragma unroll
      for (int j = 0; j < 4; ++j)
        outf[(size_t)(mb + j) * N + n] = acc[mi][ni][j] + bvl;
    }
  }
}

// ------------------------------------------------------------- attention
// r10/r13 empirical-best structure; ONLY change vs r19: the row-sum
// (16 adds + shfl_xor(32) + lrun update) moved AFTER the PV MFMA cluster
// so it executes under PV latency instead of delaying PV issue.
__global__ __launch_bounds__(128) void attn32(
    const bf16* __restrict__ Q, const bf16* __restrict__ Kb,
    const bf16* __restrict__ Vt, bf16* __restrict__ Ob,
    bf16* __restrict__ pacc, float* __restrict__ pml) {
  const float CEXP = 0.125f * 1.44269504088896f;  // scale * log2(e)
  __shared__ bf16 Ks[2][64 * 64];
  __shared__ bf16 Vs[2][64 * 64];

  int id = blockIdx.x;
  int bh = id & 31;
  int g = id >> 5;
  int qt, kt0, kt1, mode;  // mode: 0 final, 1 partial0, 2 partial1
  if (g < 16)      { qt = 16 + g;        kt0 = 0;  kt1 = 16;     mode = 1; }
  else if (g < 32) { qt = 31 - (g - 16); kt0 = 16; kt1 = qt + 1; mode = 2; }
  else             { qt = 15 - (g - 32); kt0 = 0;  kt1 = qt + 1; mode = 0; }

  int b = bh >> 4, h = bh & 15;
  int tid = threadIdx.x, lane = tid & 63, w = tid >> 6;
  int l31 = lane & 31, hi = lane >> 5, l7 = lane & 7;
  int qw = qt * 64 + w * 32;  // wave's first q-row
  int q = qw + l31;           // this lane's q-row (C col)

  bf16x8 Qf[4];
  {
    const bf16* qp = Q + ((size_t)(b * S_) + q) * D_ + h * HD_ + hi * 8;
#pragma unroll
    for (int c = 0; c < 4; ++c) Qf[c] = *(const bf16x8*)(qp + c * 16);
  }

  const bf16* kbase = Kb + (size_t)(b * S_) * D_ + h * HD_;  // row stride D_
  const bf16* vbase = Vt + (size_t)bh * HD_ * S_;            // [d][s]

  f32x16 acc0 = {}, acc1 = {};  // O^T d-tiles [0,32) and [32,64)
  float mrun = -3e38f, lrun = 0.f;

  int rl = lane >> 3;
  int schunk = (lane & 7) ^ rl;

  auto stage = [&](int buf, int kt) {
    int kk0 = kt * 64;
#pragma unroll
    for (int i = 0; i < 4; ++i) {
      int rr = w * 32 + i * 8;
      gload16(&Ks[buf][rr * 64], kbase + (size_t)(kk0 + rr + rl) * D_ + schunk * 8);
      gload16(&Vs[buf][rr * 64], vbase + (size_t)(rr + rl) * S_ + kk0 + schunk * 8);
    }
  };

  int cur = 0;
  stage(0, kt0);
  __syncthreads();

  for (int kt = kt0; kt < kt1; ++kt) {
    if (kt + 1 < kt1) stage(cur ^ 1, kt + 1);
    int kk0 = kt * 64;

    f32x16 sa0 = {}, sa1 = {};
    __builtin_amdgcn_s_setprio(1);
#pragma unroll
    for (int c = 0; c < 4; ++c) {
      bf16x8 kf0 = *(const bf16x8*)&Ks[cur][l31 * 64 + (((c * 2 + hi) ^ l7) * 8)];
      sa0 = __builtin_amdgcn_mfma_f32_32x32x16_bf16(kf0, Qf[c], sa0, 0, 0, 0);
    }
#pragma unroll
    for (int c = 0; c < 4; ++c) {
      bf16x8 kf1 = *(const bf16x8*)&Ks[cur][(32 + l31) * 64 + (((c * 2 + hi) ^ l7) * 8)];
      sa1 = __builtin_amdgcn_mfma_f32_32x32x16_bf16(kf1, Qf[c], sa1, 0, 0, 0);
    }
    __builtin_amdgcn_s_setprio(0);

    if (kk0 + 31 > qw) {
#pragma unroll
      for (int r = 0; r < 16; ++r) {
        int kg = kk0 + (r & 3) + 8 * (r >> 2) + 4 * hi;
        if (kg > q) sa0[r] = -1e9f;
      }
    }
    if (kk0 + 63 > qw) {
#pragma unroll
      for (int r = 0; r < 16; ++r) {
        int kg = kk0 + 32 + (r & 3) + 8 * (r >> 2) + 4 * hi;
        if (kg > q) sa1[r] = -1e9f;
      }
    }

    f32x16 mm = __builtin_elementwise_max(sa0, sa1);
    float tmax = fmaxf(
        fmaxf(fmaxf(fmaxf(mm[0], mm[1]), fmaxf(mm[2], mm[3])),
              fmaxf(fmaxf(mm[4], mm[5]), fmaxf(mm[6], mm[7]))),
        fmaxf(fmaxf(fmaxf(mm[8], mm[9]), fmaxf(mm[10], mm[11])),
              fmaxf(fmaxf(mm[12], mm[13]), fmaxf(mm[14], mm[15]))));
    tmax = fmaxf(tmax, __shfl_xor(tmax, 32));

    bool nofix = __all(tmax <= mrun + 16.f);
    float mnew = nofix ? mrun : fmaxf(mrun, tmax);
    float mc = mnew * CEXP;

#pragma unroll
    for (int r = 0; r < 16; ++r) {
      sa0[r] = exp2f(sa0[r] * CEXP - mc);
      sa1[r] = exp2f(sa1[r] * CEXP - mc);
    }

    // rescale acc (rare path) before PV so PV accumulates into scaled acc
    float rs = 1.f;
    if (!nofix) {
      rs = exp2f((mrun - mnew) * CEXP);
      mrun = mnew;
      acc0 *= rs;
      acc1 *= rs;
    }

    // build PV B-frags straight from the exp2 results (sum deferred)
    bf16x8 Pf[4];
#pragma unroll
    for (int c2 = 0; c2 < 4; ++c2) {
      const f32x16& pt = (c2 < 2) ? sa0 : sa1;
      const int base = (c2 & 1) * 8;
      u32 d0, d1, d2, d3;
      asm("v_cvt_pk_bf16_f32 %0, %1, %2" : "=v"(d0) : "v"(pt[base + 0]), "v"(pt[base + 1]));
      asm("v_cvt_pk_bf16_f32 %0, %1, %2" : "=v"(d1) : "v"(pt[base + 2]), "v"(pt[base + 3]));
      asm("v_cvt_pk_bf16_f32 %0, %1, %2" : "=v"(d2) : "v"(pt[base + 4]), "v"(pt[base + 5]));
      asm("v_cvt_pk_bf16_f32 %0, %1, %2" : "=v"(d3) : "v"(pt[base + 6]), "v"(pt[base + 7]));
      asm("v_permlane32_swap_b32 %0, %1" : "+v"(d0), "+v"(d2));
      asm("v_permlane32_swap_b32 %0, %1" : "+v"(d1), "+v"(d3));
      union { u32 u[4]; bf16x8 v; } un;
      un.u[0] = d0; un.u[1] = d1; un.u[2] = d2; un.u[3] = d3;
      Pf[c2] = un.v;
    }

    __builtin_amdgcn_s_setprio(1);
#pragma unroll
    for (int c2 = 0; c2 < 4; ++c2) {
      bf16x8 vf0 = *(const bf16x8*)&Vs[cur][l31 * 64 + (((c2 * 2 + hi) ^ l7) * 8)];
      acc0 = __builtin_amdgcn_mfma_f32_32x32x16_bf16(vf0, Pf[c2], acc0, 0, 0, 0);
      bf16x8 vf1 = *(const bf16x8*)&Vs[cur][(32 + l31) * 64 + (((c2 * 2 + hi) ^ l7) * 8)];
      acc1 = __builtin_amdgcn_mfma_f32_32x32x16_bf16(vf1, Pf[c2], acc1, 0, 0, 0);
    }
    __builtin_amdgcn_s_setprio(0);

    // deferred row-sum: executes under PV's MFMA latency shadow
    {
      f32x16 ss = sa0 + sa1;
      float ps = (((ss[0] + ss[1]) + (ss[2] + ss[3])) +
                  ((ss[4] + ss[5]) + (ss[6] + ss[7]))) +
                 (((ss[8] + ss[9]) + (ss[10] + ss[11])) +
                  ((ss[12] + ss[13]) + (ss[14] + ss[15])));
      ps += __shfl_xor(ps, 32);
      lrun = lrun * rs + ps;
    }

    __syncthreads();
    cur ^= 1;
  }

  if (mode == 0) {
    float inv = 1.f / lrun;
    bf16* orow = Ob + ((size_t)(b * S_) + q) * D_ + h * HD_;
#pragma unroll
    for (int dt = 0; dt < 2; ++dt) {
      const f32x16& a = dt ? acc1 : acc0;
#pragma unroll
      for (int rq = 0; rq < 4; ++rq) {
        bf16x4 o = {(bf16)(a[rq * 4 + 0] * inv), (bf16)(a[rq * 4 + 1] * inv),
                    (bf16)(a[rq * 4 + 2] * inv), (bf16)(a[rq * 4 + 3] * inv)};
        *(bf16x4*)&orow[dt * 32 + 8 * rq + 4 * hi] = o;
      }
    }
  } else {
    int tIdx = ((qt - 16) << 5) | bh;
    int part = mode - 1;
    bf16* pa = pacc + ((size_t)part * 512 + tIdx) * 4096;  // [64 q][64 d]
    int ql = w * 32 + l31;
#pragma unroll
    for (int dt = 0; dt < 2; ++dt) {
      const f32x16& a = dt ? acc1 : acc0;
#pragma unroll
      for (int rq = 0; rq < 4; ++rq) {
        bf16x4 o = {(bf16)a[rq * 4 + 0], (bf16)a[rq * 4 + 1],
                    (bf16)a[rq * 4 + 2], (bf16)a[rq * 4 + 3]};
        *(bf16x4*)&pa[ql * 64 + dt * 32 + 8 * rq + 4 * hi] = o;
      }
    }
    if (hi == 0) {
      float* pm = pml + ((size_t)part * 512 + tIdx) * 128;
      pm[ql] = mrun;
      pm[64 + ql] = lrun;
    }
  }
}

// -------------------------------------------------- combine heavy halves
__global__ __launch_bounds__(256) void attn_combine(
    const bf16* __restrict__ pacc, const float* __restrict__ pml,
    bf16* __restrict__ Ob) {
  const float CEXP = 0.125f * 1.44269504088896f;
  int tIdx = blockIdx.x;  // 0..511
  int qt = 16 + (tIdx >> 5), bh = tIdx & 31;
  int b = bh >> 4, h = bh & 15;
  int tid = threadIdx.x;
  int ql = tid >> 2, dc = tid & 3;  // 64 q-rows x 4 chunks of 16 d

  const float* m1p = pml + (size_t)tIdx * 128;
  const float* m2p = pml + (size_t)(512 + tIdx) * 128;
  float m1 = m1p[ql], l1 = m1p[64 + ql];
  float m2 = m2p[ql], l2 = m2p[64 + ql];
  float m = fmaxf(m1, m2);
  float e1 = exp2f((m1 - m) * CEXP), e2 = exp2f((m2 - m) * CEXP);
  float inv = 1.f / (e1 * l1 + e2 * l2);
  float s1 = e1 * inv, s2 = e2 * inv;

  const bf16* a1 = pacc + (size_t)tIdx * 4096 + ql * 64 + dc * 16;
  const bf16* a2 = pacc + (size_t)(512 + tIdx) * 4096 + ql * 64 + dc * 16;
  bf16x8 v1a = *(const bf16x8*)a1, v1b = *(const bf16x8*)(a1 + 8);
  bf16x8 v2a = *(const bf16x8*)a2, v2b = *(const bf16x8*)(a2 + 8);
  bf16x8 oa, ob;
#pragma unroll
  for (int j = 0; j < 8; ++j) {
    oa[j] = (bf16)((float)v1a[j] * s1 + (float)v2a[j] * s2);
    ob[j] = (bf16)((float)v1b[j] * s1 + (float)v2b[j] * s2);
  }
  int q = qt * 64 + ql;
  bf16* orow = Ob + ((size_t)(b * S_) + q) * D_ + h * HD_ + dc * 16;
  *(bf16x8*)orow = oa;
  *(bf16x8*)(orow + 8) = ob;
}

// ---------------------------------------------------------------- launch
extern "C" void kernel_launch(void* const* d_in, const int* in_sizes, int n_in,
                              void* d_out, int out_size, void* d_ws,
                              size_t ws_size, hipStream_t stream) {
  const float* x  = (const float*)d_in[0];
  const float* Wq = (const float*)d_in[1];
  const float* bq = (const float*)d_in[2];
  const float* Wk = (const float*)d_in[3];
  const float* bk = (const float*)d_in[4];
  const float* Wv = (const float*)d_in[5];
  const float* bv = (const float*)d_in[6];
  const float* Wo = (const float*)d_in[7];
  const float* bo = (const float*)d_in[8];
  float* out = (float*)d_out;

  char* ws = (char*)d_ws;
  bf16* xb  = (bf16*)(ws);                    // 8 MB: x bf16 (dead after QKV)
  bf16* wt  = (bf16*)(ws + (8u << 20));       // 8 MB: Wq^T|Wk^T|Wv^T|Wo^T bf16
  bf16* qb  = (bf16*)(ws + (16u << 20));      // 8 MB
  bf16* kb  = (bf16*)(ws + (24u << 20));      // 8 MB
  bf16* vtb = (bf16*)(ws + (32u << 20));      // 8 MB  [B][H][HD][S]
  bf16* atb = (bf16*)(ws + (40u << 20));      // 8 MB  attention out bf16
  // attn partial scratch reuses regions dead during attention:
  bf16*  pacc = (bf16*)(ws);                  // 8 MB over xb
  float* pml  = (float*)(ws + (8u << 20));    // 512 KB over Wq^T slab (dead)

  const int M = B_ * S_;  // 4096

  prep<<<dim3(2048), 256, 0, stream>>>(x, Wq, Wk, Wv, Wo, xb, wt);

  gemm_qkv<<<dim3(512), 256, 0, stream>>>(xb, wt, bq, bk, bv, qb, kb, vtb);

  attn32<<<dim3(1536), 128, 0, stream>>>(qb, kb, vtb, atb, pacc, pml);
  attn_combine<<<dim3(512), 256, 0, stream>>>(pacc, pml, atb);

  gemm128<<<dim3(8, 32), 256, 0, stream>>>(atb, wt + (3u << 20), bo, out, M, D_, D_);
}

// Round 21
// 112.162 us; speedup vs baseline: 1.0178x; 1.0178x over previous
//
#include <hip/hip_runtime.h>
#include <hip/hip_bf16.h>
#include <stdint.h>

typedef __bf16 bf16;
typedef __bf16 bf16x8 __attribute__((ext_vector_type(8)));
typedef __bf16 bf16x4 __attribute__((ext_vector_type(4)));
typedef float f32x4 __attribute__((ext_vector_type(4)));
typedef float f32x16 __attribute__((ext_vector_type(16)));
typedef unsigned int u32;

#define B_  2
#define S_  2048
#define D_  1024
#define H_  16
#define HD_ 64

typedef __attribute__((address_space(1))) uint32_t gu32;
typedef __attribute__((address_space(3))) uint32_t lu32;

__device__ __forceinline__ void gload16(void* lds, const void* g) {
  __builtin_amdgcn_global_load_lds((const gu32*)(uintptr_t)g,
                                   (lu32*)(uint32_t)(uintptr_t)lds,
                                   16, 0, 0);
}

// ---------------------------------------- prep: wtrans (ids 0..1023) + cast x
__global__ __launch_bounds__(256) void prep(
    const float* __restrict__ x,
    const float* __restrict__ w0, const float* __restrict__ w1,
    const float* __restrict__ w2, const float* __restrict__ w3,
    bf16* __restrict__ xb, bf16* __restrict__ wt) {
  __shared__ float tile[64][65];
  int id = blockIdx.x;
  if (id < 1024) {
    int z = id >> 8, rem = id & 255;
    const float* src = (z == 0) ? w0 : (z == 1) ? w1 : (z == 2) ? w2 : w3;
    bf16* dst = wt + ((size_t)z << 20);
    int x0 = (rem & 15) * 64, y0 = (rem >> 4) * 64;
    int tx = threadIdx.x & 63, ty = threadIdx.x >> 6;  // 64 x 4
#pragma unroll
    for (int r = 0; r < 16; ++r)
      tile[ty + r * 4][tx] = src[(size_t)(y0 + ty + r * 4) * D_ + x0 + tx];
    __syncthreads();
#pragma unroll
    for (int r = 0; r < 16; ++r)
      dst[(size_t)(x0 + ty + r * 4) * D_ + y0 + tx] = (bf16)tile[tx][ty + r * 4];
  } else {
    int cid = id - 1024;  // 1024 blocks x 256 threads x 4 float4 = 4M floats
    int base = cid * 1024 + threadIdx.x;
#pragma unroll
    for (int r = 0; r < 4; ++r) {
      int i = base + r * 256;
      float4 v = ((const float4*)x)[i];
      bf16x4 o = {(bf16)v.x, (bf16)v.y, (bf16)v.z, (bf16)v.w};
      ((bf16x4*)xb)[i] = o;
    }
  }
}

// ------------------------------------------------- fused QKV projection
// Pipelined K-loop (counted vmcnt(8)) + persistent grid-stride + XOR-swizzle.
__global__ __launch_bounds__(256) void gemm_qkv(
    const bf16* __restrict__ A, const bf16* __restrict__ Bt,
    const float* __restrict__ bq, const float* __restrict__ bk,
    const float* __restrict__ bv,
    bf16* __restrict__ qb, bf16* __restrict__ kb, bf16* __restrict__ vtb) {
  __shared__ __align__(16) bf16 smem[4 * 128 * 64];  // As[2] | Bs[2] = 64 KB
  const int K = D_;
  int tid = threadIdx.x;
  int lane = tid & 63, wid = tid >> 6;
  int ln15 = lane & 15, lg = lane >> 4;
  int wr = wid >> 1, wc = wid & 1;
  int rl = lane >> 3;
  int sch = (lane & 7) ^ rl;  // inverse-swizzled source chunk
  int r7 = ln15 & 7;          // row&7 of every fragment row this lane reads

  for (int tile = blockIdx.x; tile < 768; tile += 512) {
    int m0 = (tile / 24) * 128, n0g = (tile % 24) * 128;

    f32x4 acc[4][4] = {};

    auto stage = [&](int cc, int t) {
      int k0 = t * 64;
#pragma unroll
      for (int i = 0; i < 4; ++i) {
        int rr = i * 32 + wid * 8;  // 8-row group base (linear LDS dest)
        gload16(&smem[cc * 8192 + rr * 64],
                A + (size_t)(m0 + rr + rl) * K + k0 + sch * 8);
        gload16(&smem[16384 + cc * 8192 + rr * 64],
                Bt + (size_t)(n0g + rr + rl) * K + k0 + sch * 8);
      }
    };

    const int nt = K / 64;  // 16
    stage(0, 0);
    stage(1, 1);

    for (int t = 0; t < nt; ++t) {
      int cur = t & 1;
      if (t + 1 < nt) { asm volatile("s_waitcnt vmcnt(8)" ::: "memory"); }
      else            { asm volatile("s_waitcnt vmcnt(0)" ::: "memory"); }
      __builtin_amdgcn_sched_barrier(0);
      __builtin_amdgcn_s_barrier();
      __builtin_amdgcn_sched_barrier(0);

      const bf16* Asb = &smem[cur * 8192];
      const bf16* Bsb = &smem[16384 + cur * 8192];
#pragma unroll
      for (int kk = 0; kk < 64; kk += 32) {
        int chb = kk >> 3;  // chunk base (0 or 4)
        bf16x8 af[4], bfr[4];
#pragma unroll
        for (int tt = 0; tt < 4; ++tt)
          af[tt] = *(const bf16x8*)&Asb[(wr * 64 + tt * 16 + ln15) * 64 +
                                        (((chb + lg) ^ r7) * 8)];
#pragma unroll
        for (int tt = 0; tt < 4; ++tt)
          bfr[tt] = *(const bf16x8*)&Bsb[(wc * 64 + tt * 16 + ln15) * 64 +
                                         (((chb + lg) ^ r7) * 8)];
#pragma unroll
        for (int mi = 0; mi < 4; ++mi)
#pragma unroll
          for (int ni = 0; ni < 4; ++ni)
            acc[mi][ni] = __builtin_amdgcn_mfma_f32_16x16x32_bf16(
                af[mi], bfr[ni], acc[mi][ni], 0, 0, 0);
      }

      __builtin_amdgcn_s_barrier();  // reads of buf[cur] complete (reg deps)
      if (t + 2 < nt) stage(cur, t + 2);
    }

    int seg = n0g >> 10;  // block-uniform (128 | 1024)
    int n0 = n0g & 1023;

    if (seg == 2) {
      bf16 (*tr)[136] = (bf16(*)[136])smem;
#pragma unroll
      for (int ni = 0; ni < 4; ++ni) {
        int nl = wc * 64 + ni * 16 + ln15;
        float bvl = bv[n0 + nl];
#pragma unroll
        for (int mi = 0; mi < 4; ++mi) {
          int ml = wr * 64 + mi * 16 + lg * 4;
          bf16x4 pk = {(bf16)(acc[mi][ni][0] + bvl), (bf16)(acc[mi][ni][1] + bvl),
                       (bf16)(acc[mi][ni][2] + bvl), (bf16)(acc[mi][ni][3] + bvl)};
          *(bf16x4*)&tr[nl][ml] = pk;
        }
      }
      __syncthreads();
      int r = tid >> 1, hf = tid & 1;
      int n = n0 + r;
      int hh = n >> 6, dd = n & 63;
      int bb = m0 >> 11, s0c = (m0 & 2047) + hf * 64;
      bf16* dst = vtb + (((size_t)bb * H_ + hh) * HD_ + dd) * S_ + s0c;
      const bf16* srcr = &tr[r][hf * 64];
#pragma unroll
      for (int k = 0; k < 8; ++k)
        *(bf16x8*)&dst[k * 8] = *(const bf16x8*)&srcr[k * 8];
    } else {
      const float* bias = (seg == 0) ? bq : bk;
      bf16* outp = (seg == 0) ? qb : kb;
#pragma unroll
      for (int ni = 0; ni < 4; ++ni) {
        int n = n0 + wc * 64 + ni * 16 + ln15;
        float bvl = bias[n];
#pragma unroll
        for (int mi = 0; mi < 4; ++mi) {
          int mb = m0 + wr * 64 + mi * 16 + lg * 4;
#pragma unroll
          for (int j = 0; j < 4; ++j)
            outp[(size_t)(mb + j) * D_ + n] = (bf16)(acc[mi][ni][j] + bvl);
        }
      }
    }
    __syncthreads();  // protect smem before next tile's staging
  }
}

// ------------------------------------------- GEMM (O-proj), same pipeline
__global__ __launch_bounds__(256) void gemm128(
    const bf16* __restrict__ A, const bf16* __restrict__ Bt,
    const float* __restrict__ bias, float* __restrict__ outf,
    int M, int N, int K) {
  __shared__ __align__(16) bf16 smem[4 * 128 * 64];  // As[2] | Bs[2]
  int tid = threadIdx.x;
  int lane = tid & 63, wid = tid >> 6;
  int ln15 = lane & 15, lg = lane >> 4;
  int wr = wid >> 1, wc = wid & 1;
  int m0 = blockIdx.y * 128, n0 = blockIdx.x * 128;
  int rl = lane >> 3;
  int sch = (lane & 7) ^ rl;
  int r7 = ln15 & 7;

  f32x4 acc[4][4] = {};

  auto stage = [&](int cc, int t) {
    int k0 = t * 64;
#pragma unroll
    for (int i = 0; i < 4; ++i) {
      int rr = i * 32 + wid * 8;
      gload16(&smem[cc * 8192 + rr * 64],
              A + (size_t)(m0 + rr + rl) * K + k0 + sch * 8);
      gload16(&smem[16384 + cc * 8192 + rr * 64],
              Bt + (size_t)(n0 + rr + rl) * K + k0 + sch * 8);
    }
  };

  const int nt = K / 64;
  stage(0, 0);
  stage(1, 1);

  for (int t = 0; t < nt; ++t) {
    int cur = t & 1;
    if (t + 1 < nt) { asm volatile("s_waitcnt vmcnt(8)" ::: "memory"); }
    else            { asm volatile("s_waitcnt vmcnt(0)" ::: "memory"); }
    __builtin_amdgcn_sched_barrier(0);
    __builtin_amdgcn_s_barrier();
    __builtin_amdgcn_sched_barrier(0);

    const bf16* Asb = &smem[cur * 8192];
    const bf16* Bsb = &smem[16384 + cur * 8192];
#pragma unroll
    for (int kk = 0; kk < 64; kk += 32) {
      int chb = kk >> 3;
      bf16x8 af[4], bfr[4];
#pragma unroll
      for (int tt = 0; tt < 4; ++tt)
        af[tt] = *(const bf16x8*)&Asb[(wr * 64 + tt * 16 + ln15) * 64 +
                                      (((chb + lg) ^ r7) * 8)];
#pragma unroll
      for (int tt = 0; tt < 4; ++tt)
        bfr[tt] = *(const bf16x8*)&Bsb[(wc * 64 + tt * 16 + ln15) * 64 +
                                       (((chb + lg) ^ r7) * 8)];
#pragma unroll
      for (int mi = 0; mi < 4; ++mi)
#pragma unroll
        for (int ni = 0; ni < 4; ++ni)
          acc[mi][ni] = __builtin_amdgcn_mfma_f32_16x16x32_bf16(
              af[mi], bfr[ni], acc[mi][ni], 0, 0, 0);
    }

    __builtin_amdgcn_s_barrier();
    if (t + 2 < nt) stage(cur, t + 2);
  }

#pragma unroll
  for (int ni = 0; ni < 4; ++ni) {
    int n = n0 + wc * 64 + ni * 16 + ln15;
    float bvl = bias[n];
#pragma unroll
    for (int mi = 0; mi < 4; ++mi) {
      int mb = m0 + wr * 64 + mi * 16 + lg * 4;
#pragma unroll
      for (int j = 0; j < 4; ++j)
        outf[(size_t)(mb + j) * N + n] = acc[mi][ni][j] + bvl;
    }
  }
}

// ------------------------------------------------------------- attention
// (empirical-best r10/r13/r19 configuration: longest-first K-split,
// 32x32 MFMA swapped operands, in-register P, defer-max, original
// softmax ordering. r20's sum-after-PV reorder regressed; reverted.)
__global__ __launch_bounds__(128) void attn32(
    const bf16* __restrict__ Q, const bf16* __restrict__ Kb,
    const bf16* __restrict__ Vt, bf16* __restrict__ Ob,
    bf16* __restrict__ pacc, float* __restrict__ pml) {
  const float CEXP = 0.125f * 1.44269504088896f;  // scale * log2(e)
  __shared__ bf16 Ks[2][64 * 64];
  __shared__ bf16 Vs[2][64 * 64];

  int id = blockIdx.x;
  int bh = id & 31;
  int g = id >> 5;
  int qt, kt0, kt1, mode;  // mode: 0 final, 1 partial0, 2 partial1
  if (g < 16)      { qt = 16 + g;        kt0 = 0;  kt1 = 16;     mode = 1; }
  else if (g < 32) { qt = 31 - (g - 16); kt0 = 16; kt1 = qt + 1; mode = 2; }
  else             { qt = 15 - (g - 32); kt0 = 0;  kt1 = qt + 1; mode = 0; }

  int b = bh >> 4, h = bh & 15;
  int tid = threadIdx.x, lane = tid & 63, w = tid >> 6;
  int l31 = lane & 31, hi = lane >> 5, l7 = lane & 7;
  int qw = qt * 64 + w * 32;  // wave's first q-row
  int q = qw + l31;           // this lane's q-row (C col)

  bf16x8 Qf[4];
  {
    const bf16* qp = Q + ((size_t)(b * S_) + q) * D_ + h * HD_ + hi * 8;
#pragma unroll
    for (int c = 0; c < 4; ++c) Qf[c] = *(const bf16x8*)(qp + c * 16);
  }

  const bf16* kbase = Kb + (size_t)(b * S_) * D_ + h * HD_;  // row stride D_
  const bf16* vbase = Vt + (size_t)bh * HD_ * S_;            // [d][s]

  f32x16 acc0 = {}, acc1 = {};  // O^T d-tiles [0,32) and [32,64)
  float mrun = -3e38f, lrun = 0.f;

  int rl = lane >> 3;
  int schunk = (lane & 7) ^ rl;

  auto stage = [&](int buf, int kt) {
    int kk0 = kt * 64;
#pragma unroll
    for (int i = 0; i < 4; ++i) {
      int rr = w * 32 + i * 8;
      gload16(&Ks[buf][rr * 64], kbase + (size_t)(kk0 + rr + rl) * D_ + schunk * 8);
      gload16(&Vs[buf][rr * 64], vbase + (size_t)(rr + rl) * S_ + kk0 + schunk * 8);
    }
  };

  int cur = 0;
  stage(0, kt0);
  __syncthreads();

  for (int kt = kt0; kt < kt1; ++kt) {
    if (kt + 1 < kt1) stage(cur ^ 1, kt + 1);
    int kk0 = kt * 64;

    f32x16 sa0 = {}, sa1 = {};
    __builtin_amdgcn_s_setprio(1);
#pragma unroll
    for (int c = 0; c < 4; ++c) {
      bf16x8 kf0 = *(const bf16x8*)&Ks[cur][l31 * 64 + (((c * 2 + hi) ^ l7) * 8)];
      sa0 = __builtin_amdgcn_mfma_f32_32x32x16_bf16(kf0, Qf[c], sa0, 0, 0, 0);
    }
#pragma unroll
    for (int c = 0; c < 4; ++c) {
      bf16x8 kf1 = *(const bf16x8*)&Ks[cur][(32 + l31) * 64 + (((c * 2 + hi) ^ l7) * 8)];
      sa1 = __builtin_amdgcn_mfma_f32_32x32x16_bf16(kf1, Qf[c], sa1, 0, 0, 0);
    }
    __builtin_amdgcn_s_setprio(0);

    if (kk0 + 31 > qw) {
#pragma unroll
      for (int r = 0; r < 16; ++r) {
        int kg = kk0 + (r & 3) + 8 * (r >> 2) + 4 * hi;
        if (kg > q) sa0[r] = -1e9f;
      }
    }
    if (kk0 + 63 > qw) {
#pragma unroll
      for (int r = 0; r < 16; ++r) {
        int kg = kk0 + 32 + (r & 3) + 8 * (r >> 2) + 4 * hi;
        if (kg > q) sa1[r] = -1e9f;
      }
    }

    f32x16 mm = __builtin_elementwise_max(sa0, sa1);
    float tmax = fmaxf(
        fmaxf(fmaxf(fmaxf(mm[0], mm[1]), fmaxf(mm[2], mm[3])),
              fmaxf(fmaxf(mm[4], mm[5]), fmaxf(mm[6], mm[7]))),
        fmaxf(fmaxf(fmaxf(mm[8], mm[9]), fmaxf(mm[10], mm[11])),
              fmaxf(fmaxf(mm[12], mm[13]), fmaxf(mm[14], mm[15]))));
    tmax = fmaxf(tmax, __shfl_xor(tmax, 32));

    bool nofix = __all(tmax <= mrun + 16.f);
    float mnew = nofix ? mrun : fmaxf(mrun, tmax);
    float mc = mnew * CEXP;

#pragma unroll
    for (int r = 0; r < 16; ++r) {
      sa0[r] = exp2f(sa0[r] * CEXP - mc);
      sa1[r] = exp2f(sa1[r] * CEXP - mc);
    }

    f32x16 ss = sa0 + sa1;
    float ps = (((ss[0] + ss[1]) + (ss[2] + ss[3])) +
                ((ss[4] + ss[5]) + (ss[6] + ss[7]))) +
               (((ss[8] + ss[9]) + (ss[10] + ss[11])) +
                ((ss[12] + ss[13]) + (ss[14] + ss[15])));
    ps += __shfl_xor(ps, 32);

    if (nofix) {
      lrun += ps;
    } else {
      float rs = exp2f((mrun - mnew) * CEXP);
      lrun = lrun * rs + ps;
      mrun = mnew;
      acc0 *= rs;
      acc1 *= rs;
    }

    bf16x8 Pf[4];
#pragma unroll
    for (int c2 = 0; c2 < 4; ++c2) {
      const f32x16& pt = (c2 < 2) ? sa0 : sa1;
      const int base = (c2 & 1) * 8;
      u32 d0, d1, d2, d3;
      asm("v_cvt_pk_bf16_f32 %0, %1, %2" : "=v"(d0) : "v"(pt[base + 0]), "v"(pt[base + 1]));
      asm("v_cvt_pk_bf16_f32 %0, %1, %2" : "=v"(d1) : "v"(pt[base + 2]), "v"(pt[base + 3]));
      asm("v_cvt_pk_bf16_f32 %0, %1, %2" : "=v"(d2) : "v"(pt[base + 4]), "v"(pt[base + 5]));
      asm("v_cvt_pk_bf16_f32 %0, %1, %2" : "=v"(d3) : "v"(pt[base + 6]), "v"(pt[base + 7]));
      asm("v_permlane32_swap_b32 %0, %1" : "+v"(d0), "+v"(d2));
      asm("v_permlane32_swap_b32 %0, %1" : "+v"(d1), "+v"(d3));
      union { u32 u[4]; bf16x8 v; } un;
      un.u[0] = d0; un.u[1] = d1; un.u[2] = d2; un.u[3] = d3;
      Pf[c2] = un.v;
    }

    __builtin_amdgcn_s_setprio(1);
#pragma unroll
    for (int c2 = 0; c2 < 4; ++c2) {
      bf16x8 vf0 = *(const bf16x8*)&Vs[cur][l31 * 64 + (((c2 * 2 + hi) ^ l7) * 8)];
      acc0 = __builtin_amdgcn_mfma_f32_32x32x16_bf16(vf0, Pf[c2], acc0, 0, 0, 0);
      bf16x8 vf1 = *(const bf16x8*)&Vs[cur][(32 + l31) * 64 + (((c2 * 2 + hi) ^ l7) * 8)];
      acc1 = __builtin_amdgcn_mfma_f32_32x32x16_bf16(vf1, Pf[c2], acc1, 0, 0, 0);
    }
    __builtin_amdgcn_s_setprio(0);

    __syncthreads();
    cur ^= 1;
  }

  if (mode == 0) {
    float inv = 1.f / lrun;
    bf16* orow = Ob + ((size_t)(b * S_) + q) * D_ + h * HD_;
#pragma unroll
    for (int dt = 0; dt < 2; ++dt) {
      const f32x16& a = dt ? acc1 : acc0;
#pragma unroll
      for (int rq = 0; rq < 4; ++rq) {
        bf16x4 o = {(bf16)(a[rq * 4 + 0] * inv), (bf16)(a[rq * 4 + 1] * inv),
                    (bf16)(a[rq * 4 + 2] * inv), (bf16)(a[rq * 4 + 3] * inv)};
        *(bf16x4*)&orow[dt * 32 + 8 * rq + 4 * hi] = o;
      }
    }
  } else {
    int tIdx = ((qt - 16) << 5) | bh;
    int part = mode - 1;
    bf16* pa = pacc + ((size_t)part * 512 + tIdx) * 4096;  // [64 q][64 d]
    int ql = w * 32 + l31;
#pragma unroll
    for (int dt = 0; dt < 2; ++dt) {
      const f32x16& a = dt ? acc1 : acc0;
#pragma unroll
      for (int rq = 0; rq < 4; ++rq) {
        bf16x4 o = {(bf16)a[rq * 4 + 0], (bf16)a[rq * 4 + 1],
                    (bf16)a[rq * 4 + 2], (bf16)a[rq * 4 + 3]};
        *(bf16x4*)&pa[ql * 64 + dt * 32 + 8 * rq + 4 * hi] = o;
      }
    }
    if (hi == 0) {
      float* pm = pml + ((size_t)part * 512 + tIdx) * 128;
      pm[ql] = mrun;
      pm[64 + ql] = lrun;
    }
  }
}

// -------------------------------------------------- combine heavy halves
__global__ __launch_bounds__(256) void attn_combine(
    const bf16* __restrict__ pacc, const float* __restrict__ pml,
    bf16* __restrict__ Ob) {
  const float CEXP = 0.125f * 1.44269504088896f;
  int tIdx = blockIdx.x;  // 0..511
  int qt = 16 + (tIdx >> 5), bh = tIdx & 31;
  int b = bh >> 4, h = bh & 15;
  int tid = threadIdx.x;
  int ql = tid >> 2, dc = tid & 3;  // 64 q-rows x 4 chunks of 16 d

  const float* m1p = pml + (size_t)tIdx * 128;
  const float* m2p = pml + (size_t)(512 + tIdx) * 128;
  float m1 = m1p[ql], l1 = m1p[64 + ql];
  float m2 = m2p[ql], l2 = m2p[64 + ql];
  float m = fmaxf(m1, m2);
  float e1 = exp2f((m1 - m) * CEXP), e2 = exp2f((m2 - m) * CEXP);
  float inv = 1.f / (e1 * l1 + e2 * l2);
  float s1 = e1 * inv, s2 = e2 * inv;

  const bf16* a1 = pacc + (size_t)tIdx * 4096 + ql * 64 + dc * 16;
  const bf16* a2 = pacc + (size_t)(512 + tIdx) * 4096 + ql * 64 + dc * 16;
  bf16x8 v1a = *(const bf16x8*)a1, v1b = *(const bf16x8*)(a1 + 8);
  bf16x8 v2a = *(const bf16x8*)a2, v2b = *(const bf16x8*)(a2 + 8);
  bf16x8 oa, ob;
#pragma unroll
  for (int j = 0; j < 8; ++j) {
    oa[j] = (bf16)((float)v1a[j] * s1 + (float)v2a[j] * s2);
    ob[j] = (bf16)((float)v1b[j] * s1 + (float)v2b[j] * s2);
  }
  int q = qt * 64 + ql;
  bf16* orow = Ob + ((size_t)(b * S_) + q) * D_ + h * HD_ + dc * 16;
  *(bf16x8*)orow = oa;
  *(bf16x8*)(orow + 8) = ob;
}

// ---------------------------------------------------------------- launch
extern "C" void kernel_launch(void* const* d_in, const int* in_sizes, int n_in,
                              void* d_out, int out_size, void* d_ws,
                              size_t ws_size, hipStream_t stream) {
  const float* x  = (const float*)d_in[0];
  const float* Wq = (const float*)d_in[1];
  const float* bq = (const float*)d_in[2];
  const float* Wk = (const float*)d_in[3];
  const float* bk = (const float*)d_in[4];
  const float* Wv = (const float*)d_in[5];
  const float* bv = (const float*)d_in[6];
  const float* Wo = (const float*)d_in[7];
  const float* bo = (const float*)d_in[8];
  float* out = (float*)d_out;

  char* ws = (char*)d_ws;
  bf16* xb  = (bf16*)(ws);                    // 8 MB: x bf16 (dead after QKV)
  bf16* wt  = (bf16*)(ws + (8u << 20));       // 8 MB: Wq^T|Wk^T|Wv^T|Wo^T bf16
  bf16* qb  = (bf16*)(ws + (16u << 20));      // 8 MB
  bf16* kb  = (bf16*)(ws + (24u << 20));      // 8 MB
  bf16* vtb = (bf16*)(ws + (32u << 20));      // 8 MB  [B][H][HD][S]
  bf16* atb = (bf16*)(ws + (40u << 20));      // 8 MB  attention out bf16
  // attn partial scratch reuses regions dead during attention:
  bf16*  pacc = (bf16*)(ws);                  // 8 MB over xb
  float* pml  = (float*)(ws + (8u << 20));    // 512 KB over Wq^T slab (dead)

  const int M = B_ * S_;  // 4096

  prep<<<dim3(2048), 256, 0, stream>>>(x, Wq, Wk, Wv, Wo, xb, wt);

  gemm_qkv<<<dim3(512), 256, 0, stream>>>(xb, wt, bq, bk, bv, qb, kb, vtb);

  attn32<<<dim3(1536), 128, 0, stream>>>(qb, kb, vtb, atb, pacc, pml);
  attn_combine<<<dim3(512), 256, 0, stream>>>(pacc, pml, atb);

  gemm128<<<dim3(8, 32), 256, 0, stream>>>(atb, wt + (3u << 20), bo, out, M, D_, D_);
}